// Round 2
// baseline (4573.815 us; speedup 1.0000x reference)
//
#include <hip/hip_runtime.h>
#include <hip/hip_bf16.h>
#include <math.h>

typedef __hip_bfloat16 bf16;

#define BQ 1024
#define NUME 20000
#define NET 17
#define DIMT 28
#define DIME 100
#define DIM 200
#define HEADS 4
#define OH 50
#define N0 160000
#define N1 40000
#define RNODES 8192
#define E0 60000
#define E1 16000
#define KK 500000
#define DIMR 100
#define HATT 4
#define OA 50
#define DIN0 128
#define DIN1 228
#define HD 800
#define NROWS 2048

__device__ __forceinline__ float b2f(bf16 v){ return __bfloat162float(v); }
__device__ __forceinline__ bf16 f2b(float v){ return __float2bfloat16(v); }

// ---- dtype normalization ----------------------------------------------------
// 29 float tensors normalized to bf16 copies in ws (all except Wsub/Wobj/cWsub/cWobj)
static constexpr int CVT_NREG = 29;
static constexpr int CVT_N[CVT_NREG] = {
  2000000, 28, 28, 435200, 3400, 3400, 3400, 775200, 3400, 3400, 3400,
  800, 800, 40000, 200, 40000, 200, 800, 800, 160000, 200, 800, 800,
  20000, 20000, 800, 800, 20000, 20000
};
static constexpr int CVT_DIN[CVT_NREG] = {
  12,13,14,15,16,17,18,19,20,21,22,23,24,25,26,27,28,29,30,31,32,33,34,36,38,39,40,42,44
};
struct CvtSrcs { const void* p[CVT_NREG]; };

__global__ __launch_bounds__(64) void k_detect(const unsigned* tfw, unsigned* flag){
  if (threadIdx.x == 0) flag[0] = ((tfw[0] & 0xFFFFu) == 0u) ? 1u : 0u;
}

__global__ __launch_bounds__(256) void k_cvt(CvtSrcs srcs, bf16* dst, const unsigned* flagp){
  int r = blockIdx.y;
  int n = CVT_N[r];
  int i = blockIdx.x*256 + threadIdx.x;
  if (i >= n) return;
  int off = 0;
  for (int k=0;k<r;k++) off += CVT_N[k];
  bool f32m = flagp[0] != 0u;
  bf16 v;
  if (f32m) v = f2b(((const float*)srcs.p[r])[i]);
  else      v = ((const bf16*)srcs.p[r])[i];
  dst[off + i] = v;
}

__global__ __launch_bounds__(256) void k_fill_u32(unsigned* p, unsigned v, long n){
  long i = (long)blockIdx.x*256 + threadIdx.x;
  if (i < n) p[i] = v;
}

// fill masked region of out with -100 (dtype-dependent pattern & word count)
__global__ __launch_bounds__(256) void k_fill_out(void* outb, const unsigned* flagp){
  bool f32m = flagp[0] != 0u;
  long nwords = f32m ? (long)2*BQ*NUME : (long)BQ*NUME;
  long i = (long)blockIdx.x*256 + threadIdx.x;
  if (i >= nwords) return;
  unsigned* p = (unsigned*)((char*)outb + (size_t)2*BQ*NUME * (f32m ? 4 : 2));
  p[i] = f32m ? 0xC2C80000u : 0xC2C8C2C8u;
}

// wal[r][i][h] = sum_o Wg[r,i,h,o]*al[r,h,o]; war likewise
__global__ __launch_bounds__(256) void k_prep_w(const bf16* Wg, const bf16* al, const bf16* ar,
                                                float* wal, float* war, int DIN){
  int idx = blockIdx.x*256 + threadIdx.x;
  int total = NET*DIN*4;
  if (idx >= total) return;
  int h = idx & 3; int ri = idx >> 2; int i = ri % DIN; int r = ri / DIN;
  const bf16* wrow = Wg + ((size_t)(r*DIN + i))*HEADS*OH + h*OH;
  const bf16* alr = al + (size_t)(r*HEADS + h)*OH;
  const bf16* arr = ar + (size_t)(r*HEADS + h)*OH;
  float sl=0.f, sr=0.f;
  for (int o=0;o<OH;o++){ float w=b2f(wrow[o]); sl += w*b2f(alr[o]); sr += w*b2f(arr[o]); }
  wal[idx]=sl; war[idx]=sr;
}

__global__ __launch_bounds__(256) void k_bgs(const bf16* bg0, const bf16* bg1, float* bgs0, float* bgs1){
  int j = blockIdx.x*256 + threadIdx.x;
  if (j < DIM){ float s=0.f; for(int r=0;r<NET;r++) s += b2f(bg0[r*DIM+j]); bgs0[j]=s; }
  else if (j < 2*DIM){ int jj=j-DIM; float s=0.f; for(int r=0;r<NET;r++) s += b2f(bg1[r*DIM+jj]); bgs1[jj]=s; }
}

__global__ __launch_bounds__(256) void k_build_x0(const int* nid0, const int* ts_p, const bf16* emb,
                                                  const bf16* tf, const bf16* tp, bf16* x0){
  long idx = (long)blockIdx.x*256 + threadIdx.x;
  if (idx >= (long)N0*DIN0) return;
  int n = idx / DIN0, j = idx % DIN0;
  int nid = nid0[n];
  bf16 v;
  if (j < DIME) v = emb[(size_t)(nid % NUME)*DIME + j];
  else {
    float t = (float)(ts_p[0] - nid / NUME);
    int jj = j - DIME;
    v = f2b(cosf(t * b2f(tf[jj]) + b2f(tp[jj])));
  }
  x0[idx] = v;
}

__global__ __launch_bounds__(256) void k_build_x1(const int* nid0, const int* ts_p, const float* msg0,
                                                  const float* bgs0, const bf16* tf, const bf16* tp, bf16* x1){
  long idx = (long)blockIdx.x*256 + threadIdx.x;
  if (idx >= (long)N1*DIN1) return;
  int n = idx / DIN1, j = idx % DIN1;
  bf16 v;
  if (j < DIM){
    v = f2b(fmaxf((msg0[(size_t)n*DIM + j] + bgs0[j]) * (1.0f/NET), 0.0f));
  } else {
    int nid = nid0[n];
    float t = (float)(ts_p[0] - nid / NUME);
    int jj = j - DIM;
    v = f2b(cosf(t * b2f(tf[jj]) + b2f(tp[jj])));
  }
  x1[idx] = v;
}

// er[(r*nd+n)*4+h] = dot(x[n], war[r][:,h])  (bf16 out)
__global__ __launch_bounds__(256) void k_er(const bf16* x, const float* war, bf16* er, int nd, int DIN){
  int idx = blockIdx.x*256 + threadIdx.x;
  if (idx >= NET*nd) return;
  int r = idx / nd, n = idx % nd;
  const bf16* xr = x + (size_t)n*DIN;
  const float4* w = (const float4*)(war + (size_t)r*DIN*4);
  float a0=0,a1=0,a2=0,a3=0;
  for (int i=0;i<DIN;i++){
    float xv=b2f(xr[i]); float4 wv=w[i];
    a0+=xv*wv.x; a1+=xv*wv.y; a2+=xv*wv.z; a3+=xv*wv.w;
  }
  bf16* e = er + (size_t)idx*4;
  e[0]=f2b(a0); e[1]=f2b(a1); e[2]=f2b(a2); e[3]=f2b(a3);
}

// merged: e = lrelu(el + er[dst]); a = exp(e); store a (bf16); z[dst] += a
__global__ __launch_bounds__(256) void k_edge(const bf16* x, const float* wal, const bf16* er,
                                              const int* src, const int* dst, bf16* abuf, float* z,
                                              int nE, int nd, int DIN){
  int idx = blockIdx.x*256 + threadIdx.x;
  if (idx >= NET*nE) return;
  int r = idx / nE;
  int s = src[idx], d = dst[idx];
  const bf16* xr = x + (size_t)s*DIN;
  const float4* w = (const float4*)(wal + (size_t)r*DIN*4);
  float a0=0,a1=0,a2=0,a3=0;
  for (int i=0;i<DIN;i++){
    float xv=b2f(xr[i]); float4 wv=w[i];
    a0+=xv*wv.x; a1+=xv*wv.y; a2+=xv*wv.z; a3+=xv*wv.w;
  }
  float acc[4] = {a0,a1,a2,a3};
  const bf16* ern = er + ((size_t)r*nd + d)*4;
  float* zp = z + ((size_t)r*nd + d)*4;
  bf16* ao = abuf + (size_t)idx*4;
  #pragma unroll
  for (int h=0;h<4;h++){
    float v = acc[h] + b2f(ern[h]);
    v = v>0.f ? v : 0.2f*v;
    float a = expf(fminf(v, 80.f));
    ao[h] = f2b(a);
    atomicAdd(&zp[h], a);
  }
}

// message accumulate: per block 8 edges; fs computed on the fly; atomicAdd into msg
template<int DIN>
__global__ __launch_bounds__(256) void k_acc(const bf16* x, const bf16* Wg, const bf16* abuf, const float* z,
                                             const int* src, const int* dst, float* msg, int nE, int nd){
  __shared__ __align__(16) float xs[DIN*8];   // [i][e]
  __shared__ float alpha[8*4];
  __shared__ int sdst[8];
  __shared__ int ssrc[8];
  int nb = nE/8;
  int r = blockIdx.x / nb;
  int eb = (blockIdx.x % nb)*8;
  size_t ebase = (size_t)r*nE + eb;
  int t = threadIdx.x;
  if (t < 8) sdst[t] = dst[ebase + t];
  else if (t < 16) ssrc[t-8] = src[ebase + (t-8)];
  __syncthreads();
  for (int idx=t; idx<DIN*8; idx+=256){
    int i = idx >> 3, e = idx & 7;
    xs[idx] = b2f(x[(size_t)ssrc[e]*DIN + i]);
  }
  if (t < 32){
    int e = t >> 2, h = t & 3;
    float a = b2f(abuf[(ebase+e)*4 + h]);
    float zz = z[((size_t)r*nd + sdst[e])*4 + h];
    alpha[e*4+h] = a / fmaxf(zz, 1e-30f);
  }
  __syncthreads();
  if (t < 200){
    int h = t / 50;
    const bf16* wcol = Wg + (size_t)r*DIN*200 + t;
    float acc0=0,acc1=0,acc2=0,acc3=0,acc4=0,acc5=0,acc6=0,acc7=0;
    for (int i=0;i<DIN;i++){
      float w = b2f(wcol[(size_t)i*200]);
      const float4* xv = (const float4*)(xs + i*8);
      float4 xa = xv[0], xb = xv[1];
      acc0 += xa.x*w; acc1 += xa.y*w; acc2 += xa.z*w; acc3 += xa.w*w;
      acc4 += xb.x*w; acc5 += xb.y*w; acc6 += xb.z*w; acc7 += xb.w*w;
    }
    float accs[8] = {acc0,acc1,acc2,acc3,acc4,acc5,acc6,acc7};
    #pragma unroll
    for (int e=0;e<8;e++){
      atomicAdd(&msg[(size_t)sdst[e]*200 + t], alpha[e*4+h]*accs[e]);
    }
  }
}

__global__ __launch_bounds__(256) void k_hid(const float* msg1, const float* bgs1, const int* root_idx, float* hid){
  long idx = (long)blockIdx.x*256 + threadIdx.x;
  if (idx >= (long)NROWS*HD) return;
  int b = idx / HD, c = idx % HD;
  int s = c / DIM, j = c % DIM;
  int n = root_idx[b*4 + s];
  hid[idx] = fmaxf((msg1[(size_t)n*DIM + j] + bgs1[j]) * (1.0f/NET), 0.0f);
}

__global__ __launch_bounds__(256) void k_ln(const float* xin, const bf16* w, const bf16* b, float* xout){
  int row = blockIdx.x;
  const float* xr = xin + (size_t)row*HD;
  __shared__ float red[16];
  __shared__ float mu_s, rs_s;
  float s=0.f, s2=0.f;
  for (int j=threadIdx.x;j<HD;j+=256){ float v=xr[j]; s+=v; s2+=v*v; }
  for (int off=32; off; off>>=1){ s += __shfl_down(s,off); s2 += __shfl_down(s2,off); }
  int lane = threadIdx.x & 63, wid = threadIdx.x >> 6;
  if (lane==0){ red[wid]=s; red[8+wid]=s2; }
  __syncthreads();
  if (threadIdx.x==0){
    float S = red[0]+red[1]+red[2]+red[3];
    float S2 = red[8]+red[9]+red[10]+red[11];
    float mu = S * (1.0f/HD);
    float var = fmaxf(S2 * (1.0f/HD) - mu*mu, 0.f);
    mu_s = mu; rs_s = rsqrtf(var + 1e-5f);
  }
  __syncthreads();
  float mu = mu_s, rs = rs_s;
  for (int j=threadIdx.x;j<HD;j+=256){
    float v = (xr[j]-mu)*rs;
    xout[(size_t)row*HD + j] = v*b2f(w[j]) + b2f(b[j]);
  }
}

__global__ __launch_bounds__(256) void k_att(const float* xln, const bf16* Wq, const bf16* bq,
                                             const bf16* Wv, const bf16* bv, float* x2){
  __shared__ float xs[HD], qs[HD], vs[HD], att_s[64];
  int b = blockIdx.x, t = threadIdx.x;
  for (int j=t;j<HD;j+=256) xs[j] = xln[(size_t)b*HD + j];
  __syncthreads();
  for (int idx=t; idx<HD; idx+=256){
    int ha = idx/200, srow=(idx%200)/50, o=idx%50;
    const float* xr = xs + srow*200;
    const bf16* wq = Wq + (size_t)ha*DIM*OA + o;
    const bf16* wv = Wv + (size_t)ha*DIM*OA + o;
    float q=0.f, v=0.f;
    for (int e=0;e<DIM;e++){ float xv=xr[e]; q += xv*b2f(wq[(size_t)e*OA]); v += xv*b2f(wv[(size_t)e*OA]); }
    qs[idx] = q + b2f(bq[ha*OA+o]);
    vs[idx] = v + b2f(bv[ha*OA+o]);
  }
  __syncthreads();
  if (t < 64){
    int ha=t>>4, srow=(t>>2)&3, tt=t&3;
    const float* qa = qs + ha*200 + srow*50;
    const float* qb = qs + ha*200 + tt*50;
    float sc=0.f;
    for (int o=0;o<50;o++) sc += qa[o]*qb[o];
    att_s[ha*16 + srow*4 + tt] = sc;
  }
  __syncthreads();
  if (t < 16){
    int ha=t>>2, tt=t&3;
    float m=-1e30f;
    for (int srow=0;srow<4;srow++) m = fmaxf(m, att_s[ha*16+srow*4+tt]);
    float ex[4]; float zz=0.f;
    for (int srow=0;srow<4;srow++){ ex[srow]=expf(att_s[ha*16+srow*4+tt]-m); zz+=ex[srow]; }
    for (int srow=0;srow<4;srow++) att_s[ha*16+srow*4+tt] = ex[srow]/zz;
  }
  __syncthreads();
  for (int idx=t; idx<HD; idx+=256){
    int ha = idx/200, srow=(idx%200)/50, o=idx%50;
    float a=0.f;
    for (int tt=0;tt<4;tt++) a += att_s[ha*16+srow*4+tt]*vs[ha*200+tt*50+o];
    x2[(size_t)b*HD + srow*200 + ha*50 + o] = fmaxf(a, 0.f);
  }
}

__global__ __launch_bounds__(256) void k_d1(const float* x3, const bf16* Wd1, const bf16* bd1, float* x4){
  __shared__ float xs[8*HD];
  int rb = blockIdx.x*8, t = threadIdx.x;
  for (int idx=t; idx<8*HD; idx+=256) xs[idx] = x3[(size_t)rb*HD + idx];
  __syncthreads();
  if (t < DIM){
    float acc[8] = {0,0,0,0,0,0,0,0};
    for (int k=0;k<HD;k++){
      float w = b2f(Wd1[(size_t)k*DIM + t]);
      #pragma unroll
      for (int r=0;r<8;r++) acc[r] += xs[r*HD+k]*w;
    }
    float bb = b2f(bd1[t]);
    for (int r=0;r<8;r++) x4[(size_t)(rb+r)*DIM + t] = fmaxf(acc[r]+bb, 0.f);
  }
}

// preds: block = 16 rows x 512 cols; A strip (16x300) in LDS; dual-mode W read + out write
__global__ __launch_bounds__(256) void k_pred(const float* xemb, const bf16* relemb, const int* rel,
                                              const void* W, const bf16* bias, void* outb, size_t elem_off,
                                              const unsigned* flagp){
  __shared__ float As[16*304];
  bool f32m = flagp[0] != 0u;
  int rb = blockIdx.y*16;
  int cb = blockIdx.x*512;
  int t = threadIdx.x;
  for (int idx=t; idx<16*300; idx+=256){
    int r = idx/300, i = idx%300;
    int row = rb + r;
    float v = (i < DIM) ? xemb[(size_t)row*DIM + i]
                        : b2f(relemb[(size_t)rel[row]*DIMR + (i-DIM)]);
    As[r*304+i] = v;
  }
  __syncthreads();
  int c0 = cb + t, c1 = cb + 256 + t;
  bool g0 = c0 < NUME, g1 = c1 < NUME;
  float acc0[16], acc1[16];
  #pragma unroll
  for (int r=0;r<16;r++){ acc0[r]=0.f; acc1[r]=0.f; }
  if (f32m){
    const float* W32 = (const float*)W;
    for (int k=0;k<300;k++){
      float w0 = g0 ? W32[(size_t)k*NUME + c0] : 0.f;
      float w1 = g1 ? W32[(size_t)k*NUME + c1] : 0.f;
      #pragma unroll
      for (int r=0;r<16;r++){ float a = As[r*304+k]; acc0[r] += a*w0; acc1[r] += a*w1; }
    }
  } else {
    const bf16* W16 = (const bf16*)W;
    for (int k=0;k<300;k++){
      float w0 = g0 ? b2f(W16[(size_t)k*NUME + c0]) : 0.f;
      float w1 = g1 ? b2f(W16[(size_t)k*NUME + c1]) : 0.f;
      #pragma unroll
      for (int r=0;r<16;r++){ float a = As[r*304+k]; acc0[r] += a*w0; acc1[r] += a*w1; }
    }
  }
  #pragma unroll
  for (int rr=0; rr<2; rr++){
    int c = rr ? c1 : c0;
    float* acc = rr ? acc1 : acc0;
    if (c < NUME){
      float bb = b2f(bias[c]);
      for (int r=0;r<16;r++){
        size_t oi = elem_off + (size_t)(rb+r)*NUME + c;
        float val = acc[r] + bb;
        if (f32m) ((float*)outb)[oi] = val; else ((bf16*)outb)[oi] = f2b(val);
      }
    }
  }
}

// transpose (rows,cols) f32-or-bf16 -> bf16 (cols,rows)
__global__ __launch_bounds__(256) void k_transpose(const void* in, bf16* out, int rows, int cols,
                                                   const unsigned* flagp){
  __shared__ bf16 tile[32][33];
  bool f32m = flagp[0] != 0u;
  int c0 = blockIdx.x*32, r0 = blockIdx.y*32;
  int tx = threadIdx.x % 32, ty = threadIdx.x / 32;
  for (int rr=ty; rr<32; rr+=8){
    int r = r0+rr, c = c0+tx;
    if (r<rows && c<cols){
      size_t i = (size_t)r*cols + c;
      tile[rr][tx] = f32m ? f2b(((const float*)in)[i]) : ((const bf16*)in)[i];
    }
  }
  __syncthreads();
  for (int rr=ty; rr<32; rr+=8){
    int ocol = c0+rr, orow = r0+tx;
    if (ocol<cols && orow<rows) out[(size_t)ocol*rows + orow] = tile[tx][rr];
  }
}

// scattered raw values: one wave per k; dual-mode out write
__global__ __launch_bounds__(256) void k_scatter(const int* copy_rows, const int* copy_cols, const int* rel,
                                                 const float* hid, const bf16* csrel, const bf16* corel,
                                                 const bf16* cWsubT, const bf16* cWobjT,
                                                 const bf16* cbsub, const bf16* cbobj,
                                                 void* outb, const unsigned* flagp){
  bool f32m = flagp[0] != 0u;
  int wid = threadIdx.x >> 6, lane = threadIdx.x & 63;
  long k = (long)blockIdx.x*4 + wid;
  if (k >= KK) return;
  int row = copy_rows[k], col = copy_cols[k];
  const float* chrow; const bf16* re; const bf16* wt; float bias_v;
  if (row < BQ){
    chrow = hid + ((size_t)(BQ+row))*HD + 600;
    re = corel + (size_t)rel[row]*DIMR;
    wt = cWsubT + (size_t)col*300;
    bias_v = b2f(cbsub[col]);
  } else {
    int rr = row - BQ;
    chrow = hid + ((size_t)rr)*HD + 600;
    re = csrel + (size_t)rel[rr]*DIMR;
    wt = cWobjT + (size_t)col*300;
    bias_v = b2f(cbobj[col]);
  }
  float s = 0.f;
  for (int i=lane; i<300; i+=64){
    float a = (i < DIM) ? chrow[i] : b2f(re[i-DIM]);
    s += a * b2f(wt[i]);
  }
  for (int off=32; off; off>>=1) s += __shfl_down(s, off);
  if (lane==0){
    size_t oi = (size_t)2*BQ*NUME + (size_t)row*NUME + col;
    float val = s + bias_v;
    if (f32m) ((float*)outb)[oi] = val; else ((bf16*)outb)[oi] = f2b(val);
  }
}

static inline dim3 GS(long n){ return dim3((unsigned)((n + 255)/256)); }

extern "C" void kernel_launch(void* const* d_in, const int* in_sizes, int n_in,
                              void* d_out, int out_size, void* d_ws, size_t ws_size,
                              hipStream_t stream){
  const int* rel       = (const int*)d_in[2];
  const int* ts_p      = (const int*)d_in[3];
  const int* nid0      = (const int*)d_in[4];
  const int* root_idx  = (const int*)d_in[5];
  const int* src0      = (const int*)d_in[6];
  const int* dst0      = (const int*)d_in[7];
  const int* src1      = (const int*)d_in[8];
  const int* dst1      = (const int*)d_in[9];
  const int* copy_rows = (const int*)d_in[10];
  const int* copy_cols = (const int*)d_in[11];
  const void* Wsub  = d_in[35];
  const void* Wobj  = d_in[37];
  const void* cWsub = d_in[41];
  const void* cWobj = d_in[43];

  // ---- workspace layout ----
  char* base = (char*)d_ws;
  size_t off = 0;
  auto alloc = [&](size_t bytes)->char*{
    char* p = base + off; off = (off + bytes + 255) & ~(size_t)255; return p;
  };
  unsigned* flagp = (unsigned*)alloc(256);
  long cvt_total = 0; for (int i=0;i<CVT_NREG;i++) cvt_total += CVT_N[i];
  bf16* normb = (bf16*)alloc((size_t)cvt_total*2);
  bf16* x0    = (bf16*)alloc((size_t)N0*DIN0*2);       // 40.96 MB (reused for cW*T later)
  bf16* x1    = (bf16*)alloc((size_t)N1*DIN1*2);       // 18.24 MB
  float* msg0 = (float*)alloc((size_t)N1*DIM*4);       // 32 MB
  float* wal0 = (float*)alloc((size_t)NET*DIN0*4*4);
  float* war0 = (float*)alloc((size_t)NET*DIN0*4*4);
  float* wal1 = (float*)alloc((size_t)NET*DIN1*4*4);
  float* war1 = (float*)alloc((size_t)NET*DIN1*4*4);
  float* bgs0 = (float*)alloc(DIM*4);
  float* bgs1 = (float*)alloc(DIM*4);
  size_t arena = off;
  // phase-1 (GAT layer 0): er0/a0 bf16, z0 f32
  bf16*  er0 = (bf16*)(base + arena);
  bf16*  a0b = (bf16*)((char*)er0 + (size_t)NET*N1*8);
  float* z0  = (float*)((char*)a0b + (size_t)NET*E0*8);
  // phase-2 (layer 1 + tail) — overlays phase-1
  char* A = base + arena;
  bf16*  er1  = (bf16*)A;
  bf16*  a1b  = (bf16*)(A + 1114112);          // er1: 17*8192*8
  float* z1   = (float*)(A + 3290112);         // + a1b: 17*16000*8
  float* msg1 = (float*)(A + 5518336);         // + z1: 17*8192*16
  float* hid  = (float*)(A + 12071936);        // + msg1: 8192*200*4
  float* xln  = (float*)(A + 0);               // overlays er1/a1b/z1/msg1-head (all dead by k_ln)
  float* x2   = (float*)(A + 6553600);         // overlays msg1-tail/hid-head (dead by k_att)
  float* x3   = (float*)(A + 13107200);        // overlays hid-tail (dead by 2nd k_ln)
  float* x4   = (float*)(A + 19660800);        // fresh; end 21.3 MB < phase-1's 24.5 MB
  // transposed cW matrices overlay x0 (dead after layer-0 k_acc)
  bf16* cWsubT = (bf16*)x0;
  bf16* cWobjT = (bf16*)((char*)x0 + (size_t)NUME*300*2);

  // normalized tensor pointers
  long cum[CVT_NREG+1]; cum[0]=0;
  for (int i=0;i<CVT_NREG;i++) cum[i+1] = cum[i] + CVT_N[i];
  auto NP = [&](int i)->const bf16*{ return normb + cum[i]; };
  const bf16 *nEmb=NP(0), *nTf=NP(1), *nTp=NP(2), *nWg0=NP(3), *nAl0=NP(4), *nAr0=NP(5), *nBg0=NP(6),
             *nWg1=NP(7), *nAl1=NP(8), *nAr1=NP(9), *nBg1=NP(10), *nLn0w=NP(11), *nLn0b=NP(12),
             *nWq=NP(13), *nBq=NP(14), *nWv=NP(15), *nBv=NP(16), *nLn1w=NP(17), *nLn1b=NP(18),
             *nWd1=NP(19), *nBd1=NP(20), *nSrel=NP(21), *nOrel=NP(22), *nBsub=NP(23), *nBobj=NP(24),
             *nCsrel=NP(25), *nCorel=NP(26), *nCbsub=NP(27), *nCbobj=NP(28);

  // ---- phase 0: dtype detect + normalize + prep ----
  k_detect<<<dim3(1),64,0,stream>>>((const unsigned*)d_in[13], flagp);
  CvtSrcs srcs;
  for (int i=0;i<CVT_NREG;i++) srcs.p[i] = d_in[CVT_DIN[i]];
  k_cvt<<<dim3(7813, CVT_NREG),256,0,stream>>>(srcs, normb, flagp);
  k_fill_u32<<<GS((long)N1*DIM),256,0,stream>>>((unsigned*)msg0, 0u, (long)N1*DIM);
  k_fill_u32<<<GS((long)NET*N1*4),256,0,stream>>>((unsigned*)z0, 0u, (long)NET*N1*4);
  k_fill_out<<<GS((long)2*BQ*NUME),256,0,stream>>>(d_out, flagp);
  k_prep_w<<<GS(NET*DIN0*4),256,0,stream>>>(nWg0, nAl0, nAr0, wal0, war0, DIN0);
  k_prep_w<<<GS(NET*DIN1*4),256,0,stream>>>(nWg1, nAl1, nAr1, wal1, war1, DIN1);
  k_bgs<<<GS(2*DIM),256,0,stream>>>(nBg0, nBg1, bgs0, bgs1);
  k_build_x0<<<GS((long)N0*DIN0),256,0,stream>>>(nid0, ts_p, nEmb, nTf, nTp, x0);

  // ---- GAT layer 0 ----
  k_er<<<GS((long)NET*N1),256,0,stream>>>(x0, war0, er0, N1, DIN0);
  k_edge<<<GS((long)NET*E0),256,0,stream>>>(x0, wal0, er0, src0, dst0, a0b, z0, E0, N1, DIN0);
  k_acc<DIN0><<<dim3(NET*(E0/8)),256,0,stream>>>(x0, nWg0, a0b, z0, src0, dst0, msg0, E0, N1);

  // ---- build x1, GAT layer 1 ----
  k_build_x1<<<GS((long)N1*DIN1),256,0,stream>>>(nid0, ts_p, msg0, bgs0, nTf, nTp, x1);
  k_fill_u32<<<GS((long)RNODES*DIM),256,0,stream>>>((unsigned*)msg1, 0u, (long)RNODES*DIM);
  k_fill_u32<<<GS((long)NET*RNODES*4),256,0,stream>>>((unsigned*)z1, 0u, (long)NET*RNODES*4);
  k_er<<<GS((long)NET*RNODES),256,0,stream>>>(x1, war1, er1, RNODES, DIN1);
  k_edge<<<GS((long)NET*E1),256,0,stream>>>(x1, wal1, er1, src1, dst1, a1b, z1, E1, RNODES, DIN1);
  k_acc<DIN1><<<dim3(NET*(E1/8)),256,0,stream>>>(x1, nWg1, a1b, z1, src1, dst1, msg1, E1, RNODES);

  // ---- gather hid, copy-head scatter ----
  k_hid<<<GS((long)NROWS*HD),256,0,stream>>>(msg1, bgs1, root_idx, hid);
  k_transpose<<<dim3(625,10),256,0,stream>>>(cWsub, cWsubT, 300, NUME, flagp);
  k_transpose<<<dim3(625,10),256,0,stream>>>(cWobj, cWobjT, 300, NUME, flagp);
  k_scatter<<<dim3((KK+3)/4),256,0,stream>>>(copy_rows, copy_cols, rel, hid, nCsrel, nCorel,
                                             cWsubT, cWobjT, nCbsub, nCbobj, d_out, flagp);

  // ---- attention tail ----
  k_ln<<<dim3(NROWS),256,0,stream>>>(hid, nLn0w, nLn0b, xln);
  k_att<<<dim3(NROWS),256,0,stream>>>(xln, nWq, nBq, nWv, nBv, x2);
  k_ln<<<dim3(NROWS),256,0,stream>>>(x2, nLn1w, nLn1b, x3);
  k_d1<<<dim3(NROWS/8),256,0,stream>>>(x3, nWd1, nBd1, x4);

  // ---- final predictions ----
  k_pred<<<dim3(40,64),256,0,stream>>>(x4 + (size_t)BQ*DIM, nOrel, rel, Wsub, nBsub, d_out, 0, flagp);
  k_pred<<<dim3(40,64),256,0,stream>>>(x4,                  nSrel, rel, Wobj, nBobj, d_out, (size_t)BQ*NUME, flagp);
  (void)in_sizes; (void)n_in; (void)out_size; (void)ws_size;
}

// Round 3
// 4407.420 us; speedup vs baseline: 1.0378x; 1.0378x over previous
//
#include <hip/hip_runtime.h>
#include <hip/hip_bf16.h>
#include <math.h>

typedef __hip_bfloat16 bf16;
typedef __attribute__((ext_vector_type(8))) short short8;
typedef __attribute__((ext_vector_type(4))) float f32x4;

#define BQ 1024
#define NUME 20000
#define NET 17
#define DIMT 28
#define DIME 100
#define DIM 200
#define HEADS 4
#define OH 50
#define N0 160000
#define N1 40000
#define RNODES 8192
#define E0 60000
#define E1 16000
#define KK 500000
#define DIMR 100
#define HATT 4
#define OA 50
#define DIN0 128
#define DIN1 228
#define HD 800
#define NROWS 2048

__device__ __forceinline__ float b2f(bf16 v){ return __bfloat162float(v); }
__device__ __forceinline__ bf16 f2b(float v){ return __float2bfloat16(v); }

// ---- dtype normalization ----------------------------------------------------
static constexpr int CVT_NREG = 29;
static constexpr int CVT_N[CVT_NREG] = {
  2000000, 28, 28, 435200, 3400, 3400, 3400, 775200, 3400, 3400, 3400,
  800, 800, 40000, 200, 40000, 200, 800, 800, 160000, 200, 800, 800,
  20000, 20000, 800, 800, 20000, 20000
};
static constexpr int CVT_DIN[CVT_NREG] = {
  12,13,14,15,16,17,18,19,20,21,22,23,24,25,26,27,28,29,30,31,32,33,34,36,38,39,40,42,44
};
struct CvtSrcs { const void* p[CVT_NREG]; };

__global__ __launch_bounds__(64) void k_detect(const unsigned* tfw, unsigned* flag){
  if (threadIdx.x == 0) flag[0] = ((tfw[0] & 0xFFFFu) == 0u) ? 1u : 0u;
}

__global__ __launch_bounds__(256) void k_cvt(CvtSrcs srcs, bf16* dst, const unsigned* flagp){
  int r = blockIdx.y;
  int n = CVT_N[r];
  int i = blockIdx.x*256 + threadIdx.x;
  if (i >= n) return;
  int off = 0;
  for (int k=0;k<r;k++) off += CVT_N[k];
  bool f32m = flagp[0] != 0u;
  bf16 v;
  if (f32m) v = f2b(((const float*)srcs.p[r])[i]);
  else      v = ((const bf16*)srcs.p[r])[i];
  dst[off + i] = v;
}

__global__ __launch_bounds__(256) void k_fill_u32(unsigned* p, unsigned v, long n){
  long i = (long)blockIdx.x*256 + threadIdx.x;
  if (i < n) p[i] = v;
}

__global__ __launch_bounds__(256) void k_fill_out(void* outb, const unsigned* flagp){
  bool f32m = flagp[0] != 0u;
  long nwords = f32m ? (long)2*BQ*NUME : (long)BQ*NUME;
  long i = (long)blockIdx.x*256 + threadIdx.x;
  if (i >= nwords) return;
  unsigned* p = (unsigned*)((char*)outb + (size_t)2*BQ*NUME * (f32m ? 4 : 2));
  p[i] = f32m ? 0xC2C80000u : 0xC2C8C2C8u;
}

__global__ __launch_bounds__(256) void k_prep_w(const bf16* Wg, const bf16* al, const bf16* ar,
                                                float* wal, float* war, int DIN){
  int idx = blockIdx.x*256 + threadIdx.x;
  int total = NET*DIN*4;
  if (idx >= total) return;
  int h = idx & 3; int ri = idx >> 2; int i = ri % DIN; int r = ri / DIN;
  const bf16* wrow = Wg + ((size_t)(r*DIN + i))*HEADS*OH + h*OH;
  const bf16* alr = al + (size_t)(r*HEADS + h)*OH;
  const bf16* arr = ar + (size_t)(r*HEADS + h)*OH;
  float sl=0.f, sr=0.f;
  for (int o=0;o<OH;o++){ float w=b2f(wrow[o]); sl += w*b2f(alr[o]); sr += w*b2f(arr[o]); }
  wal[idx]=sl; war[idx]=sr;
}

// pack W into MFMA B-fragment order: wpk[((r*KS+ks)*13+nt)*512 + lane*8 + j]
__global__ __launch_bounds__(256) void k_pack(const bf16* Wg, bf16* wpk, int DIN, int KS){
  int idx = blockIdx.x*256 + threadIdx.x;
  int total = NET*KS*13*512;
  if (idx >= total) return;
  int j = idx & 7, lane = (idx>>3) & 63;
  int rem = idx >> 9;
  int nt = rem % 13, rks = rem / 13;
  int ks = rks % KS, r = rks / KS;
  int k = ks*32 + (lane>>4)*8 + j;
  int n = nt*16 + (lane&15);
  bf16 v = f2b(0.f);
  if (k < DIN && n < 200) v = Wg[((size_t)r*DIN + k)*200 + n];
  wpk[idx] = v;
}

__global__ __launch_bounds__(256) void k_bgs(const bf16* bg0, const bf16* bg1, float* bgs0, float* bgs1){
  int j = blockIdx.x*256 + threadIdx.x;
  if (j < DIM){ float s=0.f; for(int r=0;r<NET;r++) s += b2f(bg0[r*DIM+j]); bgs0[j]=s; }
  else if (j < 2*DIM){ int jj=j-DIM; float s=0.f; for(int r=0;r<NET;r++) s += b2f(bg1[r*DIM+jj]); bgs1[jj]=s; }
}

__global__ __launch_bounds__(256) void k_build_x0(const int* nid0, const int* ts_p, const bf16* emb,
                                                  const bf16* tf, const bf16* tp, bf16* x0){
  long idx = (long)blockIdx.x*256 + threadIdx.x;
  if (idx >= (long)N0*DIN0) return;
  int n = idx / DIN0, j = idx % DIN0;
  int nid = nid0[n];
  bf16 v;
  if (j < DIME) v = emb[(size_t)(nid % NUME)*DIME + j];
  else {
    float t = (float)(ts_p[0] - nid / NUME);
    int jj = j - DIME;
    v = f2b(cosf(t * b2f(tf[jj]) + b2f(tp[jj])));
  }
  x0[idx] = v;
}

__global__ __launch_bounds__(256) void k_build_x1(const int* nid0, const int* ts_p, const float* msg0,
                                                  const float* bgs0, const bf16* tf, const bf16* tp, bf16* x1){
  long idx = (long)blockIdx.x*256 + threadIdx.x;
  if (idx >= (long)N1*DIN1) return;
  int n = idx / DIN1, j = idx % DIN1;
  bf16 v;
  if (j < DIM){
    v = f2b(fmaxf((msg0[(size_t)n*DIM + j] + bgs0[j]) * (1.0f/NET), 0.0f));
  } else {
    int nid = nid0[n];
    float t = (float)(ts_p[0] - nid / NUME);
    int jj = j - DIM;
    v = f2b(cosf(t * b2f(tf[jj]) + b2f(tp[jj])));
  }
  x1[idx] = v;
}

__global__ __launch_bounds__(256) void k_er(const bf16* x, const float* war, bf16* er, int nd, int DIN){
  int idx = blockIdx.x*256 + threadIdx.x;
  if (idx >= NET*nd) return;
  int r = idx / nd, n = idx % nd;
  const bf16* xr = x + (size_t)n*DIN;
  const float4* w = (const float4*)(war + (size_t)r*DIN*4);
  float a0=0,a1=0,a2=0,a3=0;
  for (int i=0;i<DIN;i++){
    float xv=b2f(xr[i]); float4 wv=w[i];
    a0+=xv*wv.x; a1+=xv*wv.y; a2+=xv*wv.z; a3+=xv*wv.w;
  }
  bf16* e = er + (size_t)idx*4;
  e[0]=f2b(a0); e[1]=f2b(a1); e[2]=f2b(a2); e[3]=f2b(a3);
}

__global__ __launch_bounds__(256) void k_edge(const bf16* x, const float* wal, const bf16* er,
                                              const int* src, const int* dst, bf16* abuf, float* z,
                                              int nE, int nd, int DIN){
  int idx = blockIdx.x*256 + threadIdx.x;
  if (idx >= NET*nE) return;
  int r = idx / nE;
  int s = src[idx], d = dst[idx];
  const bf16* xr = x + (size_t)s*DIN;
  const float4* w = (const float4*)(wal + (size_t)r*DIN*4);
  float a0=0,a1=0,a2=0,a3=0;
  for (int i=0;i<DIN;i++){
    float xv=b2f(xr[i]); float4 wv=w[i];
    a0+=xv*wv.x; a1+=xv*wv.y; a2+=xv*wv.z; a3+=xv*wv.w;
  }
  float acc[4] = {a0,a1,a2,a3};
  const bf16* ern = er + ((size_t)r*nd + d)*4;
  float* zp = z + ((size_t)r*nd + d)*4;
  bf16* ao = abuf + (size_t)idx*4;
  #pragma unroll
  for (int h=0;h<4;h++){
    float v = acc[h] + b2f(ern[h]);
    v = v>0.f ? v : 0.2f*v;
    float a = expf(fminf(v, 80.f));
    ao[h] = f2b(a);
    atomicAdd(&zp[h], a);
  }
}

// ---- MFMA edge-GEMM message accumulate -------------------------------------
// Block: 64 edges of relation r. fs = xs(64xK) @ W[r](Kx200) via 16x16x32 bf16
// MFMA; epilogue: msg[dst] += alpha * fs (f32 atomics).
template<int DIN, int KS>
__global__ __launch_bounds__(256) void k_acc_mfma(const bf16* __restrict__ x, const bf16* __restrict__ wpk,
                                                  const bf16* __restrict__ abuf, const float* __restrict__ z,
                                                  const int* __restrict__ src, const int* __restrict__ dst,
                                                  float* msg, int nE, int nd){
  constexpr int KM = KS*32;
  constexpr int SR = KM + 8;          // LDS row stride (bf16): +8 breaks bank aliasing
  __shared__ bf16 xs[64*SR];
  __shared__ float alpha_s[64*4];
  __shared__ int sdst[64], ssrc[64];
  int r = blockIdx.y;
  int eb = blockIdx.x*64;
  int me = min(64, nE - eb);
  int t = threadIdx.x;
  if (t < 64){
    int v_src=0, v_dst=0;
    if (t < me){ v_src = src[(size_t)r*nE + eb + t]; v_dst = dst[(size_t)r*nE + eb + t]; }
    ssrc[t]=v_src; sdst[t]=v_dst;
  }
  __syncthreads();
  { // alpha per (edge, head)
    int m = t>>2, h = t&3;
    float al = 0.f;
    if (m < me){
      float a = b2f(abuf[((size_t)r*nE + eb + m)*4 + h]);
      float zz = z[((size_t)r*nd + sdst[m])*4 + h];
      al = a / fmaxf(zz, 1e-30f);
    }
    alpha_s[m*4+h] = al;
  }
  // stage x rows (zero-pad cols >= DIN and rows >= me)
  constexpr int CH = KM/4;           // 8-byte chunks per row
  for (int c = t; c < 64*CH; c += 256){
    int m = c / CH, j4 = c % CH;
    uint2 v = make_uint2(0u,0u);
    if (m < me && j4*4 < DIN) v = *(const uint2*)(x + (size_t)ssrc[m]*DIN + j4*4);
    *(uint2*)(xs + m*SR + j4*4) = v;
  }
  __syncthreads();

  int lane = t & 63, w = t >> 6;
  int n_idx = lane & 15, quad = lane >> 4;
  const short8* wpk8 = (const short8*)wpk;
  for (int mt=0; mt<4; mt++){
    short8 a[KS];
    const bf16* abase = xs + (size_t)(mt*16 + n_idx)*SR + quad*8;
    #pragma unroll
    for (int ks=0; ks<KS; ks++) a[ks] = *(const short8*)(abase + ks*32);
    for (int nt=w; nt<13; nt+=4){
      const short8* bp = wpk8 + (((size_t)r*KS)*13 + nt)*64 + lane;
      f32x4 acc = {0.f,0.f,0.f,0.f};
      #pragma unroll
      for (int ks=0; ks<KS; ks++){
        short8 b = bp[(size_t)ks*13*64];
        acc = __builtin_amdgcn_mfma_f32_16x16x32_bf16(a[ks], b, acc, 0, 0, 0);
      }
      int n = nt*16 + n_idx;
      if (n < 200){
        int h = n / 50;
        #pragma unroll
        for (int reg=0; reg<4; reg++){
          int m = mt*16 + quad*4 + reg;
          float val = acc[reg] * alpha_s[m*4+h];
          atomicAdd(&msg[(size_t)sdst[m]*200 + n], val);
        }
      }
    }
  }
}

__global__ __launch_bounds__(256) void k_hid(const float* msg1, const float* bgs1, const int* root_idx, float* hid){
  long idx = (long)blockIdx.x*256 + threadIdx.x;
  if (idx >= (long)NROWS*HD) return;
  int b = idx / HD, c = idx % HD;
  int s = c / DIM, j = c % DIM;
  int n = root_idx[b*4 + s];
  hid[idx] = fmaxf((msg1[(size_t)n*DIM + j] + bgs1[j]) * (1.0f/NET), 0.0f);
}

__global__ __launch_bounds__(256) void k_ln(const float* xin, const bf16* w, const bf16* b, float* xout){
  int row = blockIdx.x;
  const float* xr = xin + (size_t)row*HD;
  __shared__ float red[16];
  __shared__ float mu_s, rs_s;
  float s=0.f, s2=0.f;
  for (int j=threadIdx.x;j<HD;j+=256){ float v=xr[j]; s+=v; s2+=v*v; }
  for (int off=32; off; off>>=1){ s += __shfl_down(s,off); s2 += __shfl_down(s2,off); }
  int lane = threadIdx.x & 63, wid = threadIdx.x >> 6;
  if (lane==0){ red[wid]=s; red[8+wid]=s2; }
  __syncthreads();
  if (threadIdx.x==0){
    float S = red[0]+red[1]+red[2]+red[3];
    float S2 = red[8]+red[9]+red[10]+red[11];
    float mu = S * (1.0f/HD);
    float var = fmaxf(S2 * (1.0f/HD) - mu*mu, 0.f);
    mu_s = mu; rs_s = rsqrtf(var + 1e-5f);
  }
  __syncthreads();
  float mu = mu_s, rs = rs_s;
  for (int j=threadIdx.x;j<HD;j+=256){
    float v = (xr[j]-mu)*rs;
    xout[(size_t)row*HD + j] = v*b2f(w[j]) + b2f(b[j]);
  }
}

__global__ __launch_bounds__(256) void k_att(const float* xln, const bf16* Wq, const bf16* bq,
                                             const bf16* Wv, const bf16* bv, float* x2){
  __shared__ float xs[HD], qs[HD], vs[HD], att_s[64];
  int b = blockIdx.x, t = threadIdx.x;
  for (int j=t;j<HD;j+=256) xs[j] = xln[(size_t)b*HD + j];
  __syncthreads();
  for (int idx=t; idx<HD; idx+=256){
    int ha = idx/200, srow=(idx%200)/50, o=idx%50;
    const float* xr = xs + srow*200;
    const bf16* wq = Wq + (size_t)ha*DIM*OA + o;
    const bf16* wv = Wv + (size_t)ha*DIM*OA + o;
    float q=0.f, v=0.f;
    for (int e=0;e<DIM;e++){ float xv=xr[e]; q += xv*b2f(wq[(size_t)e*OA]); v += xv*b2f(wv[(size_t)e*OA]); }
    qs[idx] = q + b2f(bq[ha*OA+o]);
    vs[idx] = v + b2f(bv[ha*OA+o]);
  }
  __syncthreads();
  if (t < 64){
    int ha=t>>4, srow=(t>>2)&3, tt=t&3;
    const float* qa = qs + ha*200 + srow*50;
    const float* qb = qs + ha*200 + tt*50;
    float sc=0.f;
    for (int o=0;o<50;o++) sc += qa[o]*qb[o];
    att_s[ha*16 + srow*4 + tt] = sc;
  }
  __syncthreads();
  if (t < 16){
    int ha=t>>2, tt=t&3;
    float m=-1e30f;
    for (int srow=0;srow<4;srow++) m = fmaxf(m, att_s[ha*16+srow*4+tt]);
    float ex[4]; float zz=0.f;
    for (int srow=0;srow<4;srow++){ ex[srow]=expf(att_s[ha*16+srow*4+tt]-m); zz+=ex[srow]; }
    for (int srow=0;srow<4;srow++) att_s[ha*16+srow*4+tt] = ex[srow]/zz;
  }
  __syncthreads();
  for (int idx=t; idx<HD; idx+=256){
    int ha = idx/200, srow=(idx%200)/50, o=idx%50;
    float a=0.f;
    for (int tt=0;tt<4;tt++) a += att_s[ha*16+srow*4+tt]*vs[ha*200+tt*50+o];
    x2[(size_t)b*HD + srow*200 + ha*50 + o] = fmaxf(a, 0.f);
  }
}

__global__ __launch_bounds__(256) void k_d1(const float* x3, const bf16* Wd1, const bf16* bd1, float* x4){
  __shared__ float xs[8*HD];
  int rb = blockIdx.x*8, t = threadIdx.x;
  for (int idx=t; idx<8*HD; idx+=256) xs[idx] = x3[(size_t)rb*HD + idx];
  __syncthreads();
  if (t < DIM){
    float acc[8] = {0,0,0,0,0,0,0,0};
    for (int k=0;k<HD;k++){
      float w = b2f(Wd1[(size_t)k*DIM + t]);
      #pragma unroll
      for (int r=0;r<8;r++) acc[r] += xs[r*HD+k]*w;
    }
    float bb = b2f(bd1[t]);
    for (int r=0;r<8;r++) x4[(size_t)(rb+r)*DIM + t] = fmaxf(acc[r]+bb, 0.f);
  }
}

__global__ __launch_bounds__(256) void k_pred(const float* xemb, const bf16* relemb, const int* rel,
                                              const void* W, const bf16* bias, void* outb, size_t elem_off,
                                              const unsigned* flagp){
  __shared__ float As[16*304];
  bool f32m = flagp[0] != 0u;
  int rb = blockIdx.y*16;
  int cb = blockIdx.x*512;
  int t = threadIdx.x;
  for (int idx=t; idx<16*300; idx+=256){
    int r = idx/300, i = idx%300;
    int row = rb + r;
    float v = (i < DIM) ? xemb[(size_t)row*DIM + i]
                        : b2f(relemb[(size_t)rel[row]*DIMR + (i-DIM)]);
    As[r*304+i] = v;
  }
  __syncthreads();
  int c0 = cb + t, c1 = cb + 256 + t;
  bool g0 = c0 < NUME, g1 = c1 < NUME;
  float acc0[16], acc1[16];
  #pragma unroll
  for (int r=0;r<16;r++){ acc0[r]=0.f; acc1[r]=0.f; }
  if (f32m){
    const float* W32 = (const float*)W;
    for (int k=0;k<300;k++){
      float w0 = g0 ? W32[(size_t)k*NUME + c0] : 0.f;
      float w1 = g1 ? W32[(size_t)k*NUME + c1] : 0.f;
      #pragma unroll
      for (int r=0;r<16;r++){ float a = As[r*304+k]; acc0[r] += a*w0; acc1[r] += a*w1; }
    }
  } else {
    const bf16* W16 = (const bf16*)W;
    for (int k=0;k<300;k++){
      float w0 = g0 ? b2f(W16[(size_t)k*NUME + c0]) : 0.f;
      float w1 = g1 ? b2f(W16[(size_t)k*NUME + c1]) : 0.f;
      #pragma unroll
      for (int r=0;r<16;r++){ float a = As[r*304+k]; acc0[r] += a*w0; acc1[r] += a*w1; }
    }
  }
  #pragma unroll
  for (int rr=0; rr<2; rr++){
    int c = rr ? c1 : c0;
    float* acc = rr ? acc1 : acc0;
    if (c < NUME){
      float bb = b2f(bias[c]);
      for (int r=0;r<16;r++){
        size_t oi = elem_off + (size_t)(rb+r)*NUME + c;
        float val = acc[r] + bb;
        if (f32m) ((float*)outb)[oi] = val; else ((bf16*)outb)[oi] = f2b(val);
      }
    }
  }
}

__global__ __launch_bounds__(256) void k_transpose(const void* in, bf16* out, int rows, int cols,
                                                   const unsigned* flagp){
  __shared__ bf16 tile[32][33];
  bool f32m = flagp[0] != 0u;
  int c0 = blockIdx.x*32, r0 = blockIdx.y*32;
  int tx = threadIdx.x % 32, ty = threadIdx.x / 32;
  for (int rr=ty; rr<32; rr+=8){
    int r = r0+rr, c = c0+tx;
    if (r<rows && c<cols){
      size_t i = (size_t)r*cols + c;
      tile[rr][tx] = f32m ? f2b(((const float*)in)[i]) : ((const bf16*)in)[i];
    }
  }
  __syncthreads();
  for (int rr=ty; rr<32; rr+=8){
    int ocol = c0+rr, orow = r0+tx;
    if (ocol<cols && orow<rows) out[(size_t)ocol*rows + orow] = tile[tx][rr];
  }
}

__global__ __launch_bounds__(256) void k_scatter(const int* copy_rows, const int* copy_cols, const int* rel,
                                                 const float* hid, const bf16* csrel, const bf16* corel,
                                                 const bf16* cWsubT, const bf16* cWobjT,
                                                 const bf16* cbsub, const bf16* cbobj,
                                                 void* outb, const unsigned* flagp){
  bool f32m = flagp[0] != 0u;
  int wid = threadIdx.x >> 6, lane = threadIdx.x & 63;
  long k = (long)blockIdx.x*4 + wid;
  if (k >= KK) return;
  int row = copy_rows[k], col = copy_cols[k];
  const float* chrow; const bf16* re; const bf16* wt; float bias_v;
  if (row < BQ){
    chrow = hid + ((size_t)(BQ+row))*HD + 600;
    re = corel + (size_t)rel[row]*DIMR;
    wt = cWsubT + (size_t)col*300;
    bias_v = b2f(cbsub[col]);
  } else {
    int rr = row - BQ;
    chrow = hid + ((size_t)rr)*HD + 600;
    re = csrel + (size_t)rel[rr]*DIMR;
    wt = cWobjT + (size_t)col*300;
    bias_v = b2f(cbobj[col]);
  }
  float s = 0.f;
  for (int i=lane; i<300; i+=64){
    float a = (i < DIM) ? chrow[i] : b2f(re[i-DIM]);
    s += a * b2f(wt[i]);
  }
  for (int off=32; off; off>>=1) s += __shfl_down(s, off);
  if (lane==0){
    size_t oi = (size_t)2*BQ*NUME + (size_t)row*NUME + col;
    float val = s + bias_v;
    if (f32m) ((float*)outb)[oi] = val; else ((bf16*)outb)[oi] = f2b(val);
  }
}

static inline dim3 GS(long n){ return dim3((unsigned)((n + 255)/256)); }

extern "C" void kernel_launch(void* const* d_in, const int* in_sizes, int n_in,
                              void* d_out, int out_size, void* d_ws, size_t ws_size,
                              hipStream_t stream){
  const int* rel       = (const int*)d_in[2];
  const int* ts_p      = (const int*)d_in[3];
  const int* nid0      = (const int*)d_in[4];
  const int* root_idx  = (const int*)d_in[5];
  const int* src0      = (const int*)d_in[6];
  const int* dst0      = (const int*)d_in[7];
  const int* src1      = (const int*)d_in[8];
  const int* dst1      = (const int*)d_in[9];
  const int* copy_rows = (const int*)d_in[10];
  const int* copy_cols = (const int*)d_in[11];
  const void* Wsub  = d_in[35];
  const void* Wobj  = d_in[37];
  const void* cWsub = d_in[41];
  const void* cWobj = d_in[43];

  // ---- workspace layout ----
  char* base = (char*)d_ws;
  size_t off = 0;
  auto alloc = [&](size_t bytes)->char*{
    char* p = base + off; off = (off + bytes + 255) & ~(size_t)255; return p;
  };
  unsigned* flagp = (unsigned*)alloc(256);
  long cvt_total = 0; for (int i=0;i<CVT_NREG;i++) cvt_total += CVT_N[i];
  bf16* normb = (bf16*)alloc((size_t)cvt_total*2);
  bf16* x0    = (bf16*)alloc((size_t)N0*DIN0*2);       // 40.96 MB (reused for cW*T later)
  bf16* x1    = (bf16*)alloc((size_t)N1*DIN1*2);       // 18.24 MB
  float* msg0 = (float*)alloc((size_t)N1*DIM*4);       // 32 MB
  float* wal0 = (float*)alloc((size_t)NET*DIN0*4*4);
  float* war0 = (float*)alloc((size_t)NET*DIN0*4*4);
  float* wal1 = (float*)alloc((size_t)NET*DIN1*4*4);
  float* war1 = (float*)alloc((size_t)NET*DIN1*4*4);
  float* bgs0 = (float*)alloc(DIM*4);
  float* bgs1 = (float*)alloc(DIM*4);
  bf16* wpk0  = (bf16*)alloc((size_t)NET*4*13*512*2);  // 0.91 MB
  bf16* wpk1  = (bf16*)alloc((size_t)NET*8*13*512*2);  // 1.81 MB
  size_t arena = off;
  // phase-1 (GAT layer 0): er0/a0 bf16, z0 f32
  bf16*  er0 = (bf16*)(base + arena);
  bf16*  a0b = (bf16*)((char*)er0 + (size_t)NET*N1*8);
  float* z0  = (float*)((char*)a0b + (size_t)NET*E0*8);
  // phase-2 (layer 1 + tail) — overlays phase-1
  char* A = base + arena;
  bf16*  er1  = (bf16*)A;
  bf16*  a1b  = (bf16*)(A + 1114112);          // er1: 17*8192*8
  float* z1   = (float*)(A + 3290112);         // + a1b: 17*16000*8
  float* msg1 = (float*)(A + 5518336);         // + z1: 17*8192*16
  float* hid  = (float*)(A + 12071936);        // + msg1: 8192*200*4
  float* xln  = (float*)(A + 0);               // overlays er1/a1b/z1/msg1-head (dead by k_ln)
  float* x2   = (float*)(A + 6553600);
  float* x3   = (float*)(A + 13107200);
  float* x4   = (float*)(A + 19660800);
  bf16* cWsubT = (bf16*)x0;
  bf16* cWobjT = (bf16*)((char*)x0 + (size_t)NUME*300*2);

  long cum[CVT_NREG+1]; cum[0]=0;
  for (int i=0;i<CVT_NREG;i++) cum[i+1] = cum[i] + CVT_N[i];
  auto NP = [&](int i)->const bf16*{ return normb + cum[i]; };
  const bf16 *nEmb=NP(0), *nTf=NP(1), *nTp=NP(2), *nWg0=NP(3), *nAl0=NP(4), *nAr0=NP(5), *nBg0=NP(6),
             *nWg1=NP(7), *nAl1=NP(8), *nAr1=NP(9), *nBg1=NP(10), *nLn0w=NP(11), *nLn0b=NP(12),
             *nWq=NP(13), *nBq=NP(14), *nWv=NP(15), *nBv=NP(16), *nLn1w=NP(17), *nLn1b=NP(18),
             *nWd1=NP(19), *nBd1=NP(20), *nSrel=NP(21), *nOrel=NP(22), *nBsub=NP(23), *nBobj=NP(24),
             *nCsrel=NP(25), *nCorel=NP(26), *nCbsub=NP(27), *nCbobj=NP(28);

  // ---- phase 0: dtype detect + normalize + prep ----
  k_detect<<<dim3(1),64,0,stream>>>((const unsigned*)d_in[13], flagp);
  CvtSrcs srcs;
  for (int i=0;i<CVT_NREG;i++) srcs.p[i] = d_in[CVT_DIN[i]];
  k_cvt<<<dim3(7813, CVT_NREG),256,0,stream>>>(srcs, normb, flagp);
  k_fill_u32<<<GS((long)N1*DIM),256,0,stream>>>((unsigned*)msg0, 0u, (long)N1*DIM);
  k_fill_u32<<<GS((long)NET*N1*4),256,0,stream>>>((unsigned*)z0, 0u, (long)NET*N1*4);
  k_fill_out<<<GS((long)2*BQ*NUME),256,0,stream>>>(d_out, flagp);
  k_prep_w<<<GS(NET*DIN0*4),256,0,stream>>>(nWg0, nAl0, nAr0, wal0, war0, DIN0);
  k_prep_w<<<GS(NET*DIN1*4),256,0,stream>>>(nWg1, nAl1, nAr1, wal1, war1, DIN1);
  k_pack<<<GS((long)NET*4*13*512),256,0,stream>>>(nWg0, wpk0, DIN0, 4);
  k_pack<<<GS((long)NET*8*13*512),256,0,stream>>>(nWg1, wpk1, DIN1, 8);
  k_bgs<<<GS(2*DIM),256,0,stream>>>(nBg0, nBg1, bgs0, bgs1);
  k_build_x0<<<GS((long)N0*DIN0),256,0,stream>>>(nid0, ts_p, nEmb, nTf, nTp, x0);

  // ---- GAT layer 0 ----
  k_er<<<GS((long)NET*N1),256,0,stream>>>(x0, war0, er0, N1, DIN0);
  k_edge<<<GS((long)NET*E0),256,0,stream>>>(x0, wal0, er0, src0, dst0, a0b, z0, E0, N1, DIN0);
  k_acc_mfma<DIN0,4><<<dim3((E0+63)/64, NET),256,0,stream>>>(x0, wpk0, a0b, z0, src0, dst0, msg0, E0, N1);

  // ---- build x1, GAT layer 1 ----
  k_build_x1<<<GS((long)N1*DIN1),256,0,stream>>>(nid0, ts_p, msg0, bgs0, nTf, nTp, x1);
  k_fill_u32<<<GS((long)RNODES*DIM),256,0,stream>>>((unsigned*)msg1, 0u, (long)RNODES*DIM);
  k_fill_u32<<<GS((long)NET*RNODES*4),256,0,stream>>>((unsigned*)z1, 0u, (long)NET*RNODES*4);
  k_er<<<GS((long)NET*RNODES),256,0,stream>>>(x1, war1, er1, RNODES, DIN1);
  k_edge<<<GS((long)NET*E1),256,0,stream>>>(x1, wal1, er1, src1, dst1, a1b, z1, E1, RNODES, DIN1);
  k_acc_mfma<DIN1,8><<<dim3((E1+63)/64, NET),256,0,stream>>>(x1, wpk1, a1b, z1, src1, dst1, msg1, E1, RNODES);

  // ---- gather hid, copy-head scatter ----
  k_hid<<<GS((long)NROWS*HD),256,0,stream>>>(msg1, bgs1, root_idx, hid);
  k_transpose<<<dim3(625,10),256,0,stream>>>(cWsub, cWsubT, 300, NUME, flagp);
  k_transpose<<<dim3(625,10),256,0,stream>>>(cWobj, cWobjT, 300, NUME, flagp);
  k_scatter<<<dim3((KK+3)/4),256,0,stream>>>(copy_rows, copy_cols, rel, hid, nCsrel, nCorel,
                                             cWsubT, cWobjT, nCbsub, nCbobj, d_out, flagp);

  // ---- attention tail ----
  k_ln<<<dim3(NROWS),256,0,stream>>>(hid, nLn0w, nLn0b, xln);
  k_att<<<dim3(NROWS),256,0,stream>>>(xln, nWq, nBq, nWv, nBv, x2);
  k_ln<<<dim3(NROWS),256,0,stream>>>(x2, nLn1w, nLn1b, x3);
  k_d1<<<dim3(NROWS/8),256,0,stream>>>(x3, nWd1, nBd1, x4);

  // ---- final predictions ----
  k_pred<<<dim3(40,64),256,0,stream>>>(x4 + (size_t)BQ*DIM, nOrel, rel, Wsub, nBsub, d_out, 0, flagp);
  k_pred<<<dim3(40,64),256,0,stream>>>(x4,                  nSrel, rel, Wobj, nBobj, d_out, (size_t)BQ*NUME, flagp);
  (void)in_sizes; (void)n_in; (void)out_size; (void)ws_size;
}